// Round 3
// baseline (569.968 us; speedup 1.0000x reference)
//
#include <hip/hip_runtime.h>
#include <hip/hip_bf16.h>
#include <stdint.h>

// Problem constants
constexpr int BB = 4, TT = 2048, CC = 1024, HH = 16, DD = 64;

typedef __bf16 bf16_t;
typedef bf16_t bf16x8 __attribute__((ext_vector_type(8)));
typedef float f32x4 __attribute__((ext_vector_type(4)));

__device__ __forceinline__ unsigned short f2bf(float f) {
    union { float f; unsigned int u; } v; v.f = f;
    unsigned int u = v.u;
    unsigned int r = u + 0x7fffu + ((u >> 16) & 1u);
    return (unsigned short)(r >> 16);
}

__device__ __forceinline__ f32x4 mfma16(bf16x8 a, bf16x8 b, f32x4 c) {
    return __builtin_amdgcn_mfma_f32_16x16x32_bf16(a, b, c, 0, 0, 0);
}

#define LOAD_LDS16(g, l)                                                      \
    __builtin_amdgcn_global_load_lds(                                         \
        (const __attribute__((address_space(1))) void*)(g),                   \
        (__attribute__((address_space(3))) void*)(l), 16, 0, 0)

// ---------------- f32 -> bf16 convert (n % 4 == 0) ----------------
__global__ __launch_bounds__(256) void cvt_bf16(const float* __restrict__ in,
                                                unsigned short* __restrict__ out,
                                                long n) {
    long i = ((long)blockIdx.x * blockDim.x + threadIdx.x) * 4;
    long stride = (long)gridDim.x * blockDim.x * 4;
    for (; i < n; i += stride) {
        float4 v = *(const float4*)(in + i);
        ushort4 o;
        o.x = f2bf(v.x); o.y = f2bf(v.y); o.z = f2bf(v.z); o.w = f2bf(v.w);
        *(ushort4*)(out + i) = o;
    }
}

// ---------------- GEMM: C[m,n] = sum_k A[m,k]*Bw[n,k] + bias[n] ----------------
template <int MODE>
__global__ __launch_bounds__(256, 2) void gemm_bt(
    const unsigned short* __restrict__ A,    // [M][K] bf16
    const unsigned short* __restrict__ Bw,   // [N][K] bf16
    const float* __restrict__ bias,          // [N]
    unsigned short* __restrict__ qb, unsigned short* __restrict__ kb,
    unsigned short* __restrict__ vtb, float* __restrict__ outf,
    int M, int N, int K) {
    __shared__ unsigned short As[2][128 * 32];
    __shared__ unsigned short Bs[2][128 * 32];
    const int tid = threadIdx.x;
    const int w = tid >> 6, lane = tid & 63;
    const int g = lane >> 4, q16 = lane & 15;
    const int wr = w >> 1, wc = w & 1;
    const int mbase = blockIdx.x * 128;
    const int nbase = blockIdx.y * 128;
    const int srow = lane >> 2;
    const int scol = (lane & 3) * 8;

    f32x4 acc[4][4];
#pragma unroll
    for (int i = 0; i < 4; ++i)
#pragma unroll
        for (int j = 0; j < 4; ++j) acc[i][j] = (f32x4){0.f, 0.f, 0.f, 0.f};

    const int nk = K >> 5;

    auto stage = [&](int buf, int t) {
        const int k0 = t << 5;
#pragma unroll
        for (int ii = 0; ii < 2; ++ii) {
            const int i = w + ii * 4;
            const unsigned short* ga =
                A + (long)(mbase + i * 16 + srow) * K + k0 + scol;
            LOAD_LDS16(ga, &As[buf][i * 512]);
            const unsigned short* gb =
                Bw + (long)(nbase + i * 16 + srow) * K + k0 + scol;
            LOAD_LDS16(gb, &Bs[buf][i * 512]);
        }
    };

    stage(0, 0);
    __syncthreads();
    int cur = 0;
    for (int t = 0; t < nk; ++t) {
        if (t + 1 < nk) stage(cur ^ 1, t + 1);
        bf16x8 af[4], bfr[4];
#pragma unroll
        for (int mi = 0; mi < 4; ++mi)
            af[mi] = *(const bf16x8*)&As[cur][(wr * 64 + mi * 16 + q16) * 32 + 8 * g];
#pragma unroll
        for (int ni = 0; ni < 4; ++ni)
            bfr[ni] = *(const bf16x8*)&Bs[cur][(wc * 64 + ni * 16 + q16) * 32 + 8 * g];
#pragma unroll
        for (int mi = 0; mi < 4; ++mi)
#pragma unroll
            for (int ni = 0; ni < 4; ++ni)
                acc[mi][ni] = mfma16(af[mi], bfr[ni], acc[mi][ni]);
        __syncthreads();
        cur ^= 1;
    }

#pragma unroll
    for (int mi = 0; mi < 4; ++mi) {
#pragma unroll
        for (int ni = 0; ni < 4; ++ni) {
            const int n = nbase + wc * 64 + ni * 16 + q16;
            const float bv = bias[n];
#pragma unroll
            for (int r = 0; r < 4; ++r) {
                const int m = mbase + wr * 64 + mi * 16 + 4 * g + r;
                const float val = acc[mi][ni][r] + bv;
                if (MODE == 0) {
                    const int which = n >> 10, rem = n & 1023;
                    const int h = rem >> 6, d = rem & 63;
                    const int b = m >> 11, t = m & 2047;
                    const long bh = (long)(b * HH + h);
                    if (which == 0)
                        qb[(bh * TT + t) * DD + d] = f2bf(val * 0.125f);
                    else if (which == 1)
                        kb[(bh * TT + t) * DD + d] = f2bf(val);
                    else
                        vtb[(bh * DD + d) * TT + t] = f2bf(val);
                } else {
                    outf[(long)m * N + n] = val;
                }
            }
        }
    }
}

// ---------------- causal flash attention (swapped QK^T) ----------------
// grid: (T/64, B*H), block 256 (4 waves); wave owns 16 q-rows, KVBLK=64.
// Swapped: p = mfma(K_frag, Q_frag) -> D[row=k_local, col=q]. Each lane owns
// ONE q-row (q = qbase + (lane&15)); k runs over 16 registers -> row max/sum
// are in-register + 2 shfl_xor (16, 32). m/l/fs are per-lane scalars.
// P-buffer stride 72 shorts (64 row + 8 pad): rows no longer overlap (R2 bug),
// b128 reads map 8 lanes/4-bank-group = throughput-minimal; 8B writes 2-way.
__global__ __launch_bounds__(256, 3) void attn_fwd(
    const unsigned short* __restrict__ qb, const unsigned short* __restrict__ kb,
    const unsigned short* __restrict__ vtb, unsigned short* __restrict__ attb) {
    __shared__ __align__(16) unsigned short plds[4][16 * 72];  // stride 72 shorts
    const int tid = threadIdx.x;
    const int w = tid >> 6, lane = tid & 63;
    const int g = lane >> 4, q16 = lane & 15;
    const int bh = blockIdx.y;
    const int b = bh >> 4, h = bh & 15;
    const int qbase = blockIdx.x * 64 + w * 16;

    const unsigned short* Q = qb + (long)bh * TT * DD;
    const unsigned short* Kp = kb + (long)bh * TT * DD;
    const unsigned short* Vt = vtb + (long)bh * DD * TT;

    // Q as B-fragment: lane loads Q row (qbase+q16), k-slice 8g (+32)
    bf16x8 aq0 = *(const bf16x8*)&Q[(qbase + q16) * DD + 8 * g];
    bf16x8 aq1 = *(const bf16x8*)&Q[(qbase + q16) * DD + 32 + 8 * g];

    f32x4 acc[4];
#pragma unroll
    for (int i = 0; i < 4; ++i) acc[i] = (f32x4){0.f, 0.f, 0.f, 0.f};
    float mrow = -1e30f, lrow = 0.f;  // per-lane: this lane's q-row stats

    const int nkt = (qbase + 16 + 63) >> 6;  // 64-key tiles
    for (int kt = 0; kt < nkt; ++kt) {
        const int kbase = kt * 64;
        f32x4 p[4];
#pragma unroll
        for (int s = 0; s < 4; ++s) p[s] = (f32x4){0.f, 0.f, 0.f, 0.f};
        // QK^T swapped: A = K rows (kbase+16s+q16), B = Q
#pragma unroll
        for (int s = 0; s < 4; ++s) {
            bf16x8 bk0 = *(const bf16x8*)&Kp[(kbase + 16 * s + q16) * DD + 8 * g];
            bf16x8 bk1 = *(const bf16x8*)&Kp[(kbase + 16 * s + q16) * DD + 32 + 8 * g];
            p[s] = mfma16(bk0, aq0, p[s]);
            p[s] = mfma16(bk1, aq1, p[s]);
        }
        const int q = qbase + q16;
        if (kt == nkt - 1) {  // only the last tile can contain k > q
#pragma unroll
            for (int s = 0; s < 4; ++s)
#pragma unroll
                for (int r = 0; r < 4; ++r)
                    if (kbase + 16 * s + 4 * g + r > q) p[s][r] = -1e30f;
        }
        // row max: in-register (16 vals) + xor over lanes sharing q16
        float t = fmaxf(fmaxf(p[0][0], p[0][1]), fmaxf(p[0][2], p[0][3]));
#pragma unroll
        for (int s = 1; s < 4; ++s)
            t = fmaxf(t, fmaxf(fmaxf(p[s][0], p[s][1]), fmaxf(p[s][2], p[s][3])));
        t = fmaxf(t, __shfl_xor(t, 16));
        t = fmaxf(t, __shfl_xor(t, 32));
        const float nm = fmaxf(mrow, t);
        const float fs = __expf(mrow - nm);
        mrow = nm;
        float ssum = 0.f;
#pragma unroll
        for (int s = 0; s < 4; ++s)
#pragma unroll
            for (int r = 0; r < 4; ++r) {
                p[s][r] = __expf(p[s][r] - nm);
                ssum += p[s][r];
            }
        ssum += __shfl_xor(ssum, 16);
        ssum += __shfl_xor(ssum, 32);
        lrow = lrow * fs + ssum;
        // broadcast fs into acc layout (q = qbase + 4g + r)
        float fr[4];
#pragma unroll
        for (int r = 0; r < 4; ++r) fr[r] = __shfl(fs, 4 * g + r);
#pragma unroll
        for (int ni = 0; ni < 4; ++ni)
#pragma unroll
            for (int r = 0; r < 4; ++r) acc[ni][r] *= fr[r];
        // P -> LDS: lane holds P[q=q16][k=16s+4g+r]; packed 8B writes
#pragma unroll
        for (int s = 0; s < 4; ++s) {
            ushort4 pk;
            pk.x = f2bf(p[s][0]); pk.y = f2bf(p[s][1]);
            pk.z = f2bf(p[s][2]); pk.w = f2bf(p[s][3]);
            *(ushort4*)&plds[w][q16 * 72 + 16 * s + 4 * g] = pk;
        }
        bf16x8 pa0 = *(const bf16x8*)&plds[w][q16 * 72 + 8 * g];
        bf16x8 pa1 = *(const bf16x8*)&plds[w][q16 * 72 + 32 + 8 * g];
        // PV: A = P[q][k], B = V^T rows (d), cols k
#pragma unroll
        for (int ni = 0; ni < 4; ++ni) {
            bf16x8 bv0 = *(const bf16x8*)&Vt[(ni * 16 + q16) * TT + kbase + 8 * g];
            bf16x8 bv1 = *(const bf16x8*)&Vt[(ni * 16 + q16) * TT + kbase + 32 + 8 * g];
            acc[ni] = mfma16(pa0, bv0, acc[ni]);
            acc[ni] = mfma16(pa1, bv1, acc[ni]);
        }
    }
    // broadcast lrow into acc layout, write out
    float inv[4];
#pragma unroll
    for (int r = 0; r < 4; ++r) inv[r] = 1.0f / __shfl(lrow, 4 * g + r);
#pragma unroll
    for (int ni = 0; ni < 4; ++ni)
#pragma unroll
        for (int r = 0; r < 4; ++r) {
            const int q = qbase + 4 * g + r;
            const int d = ni * 16 + q16;
            attb[(((long)b * TT + q) * HH + h) * DD + d] =
                f2bf(acc[ni][r] * inv[r]);
        }
}

extern "C" void kernel_launch(void* const* d_in, const int* in_sizes, int n_in,
                              void* d_out, int out_size, void* d_ws, size_t ws_size,
                              hipStream_t stream) {
    const float* x = (const float*)d_in[0];
    const float* Wqkv = (const float*)d_in[1];
    const float* bqkv = (const float*)d_in[2];
    const float* Wproj = (const float*)d_in[3];
    const float* bproj = (const float*)d_in[4];
    float* out = (float*)d_out;

    char* ws = (char*)d_ws;
    unsigned short* xb = (unsigned short*)(ws);                  // 16 MB (reused as attb)
    unsigned short* wqkvb = (unsigned short*)(ws + (16l << 20)); // 6 MB
    unsigned short* wprojb = (unsigned short*)(ws + (22l << 20));// 2 MB
    unsigned short* qb = (unsigned short*)(ws + (24l << 20));    // 16 MB
    unsigned short* kb = (unsigned short*)(ws + (40l << 20));    // 16 MB
    unsigned short* vtb = (unsigned short*)(ws + (56l << 20));   // 16 MB
    unsigned short* attb = xb;  // x dead after QKV GEMM; reuse

    cvt_bf16<<<2048, 256, 0, stream>>>(x, xb, (long)BB * TT * CC);
    cvt_bf16<<<2048, 256, 0, stream>>>(Wqkv, wqkvb, (long)3 * CC * CC);
    cvt_bf16<<<1024, 256, 0, stream>>>(Wproj, wprojb, (long)CC * CC);

    gemm_bt<0><<<dim3(64, 24), 256, 0, stream>>>(xb, wqkvb, bqkv, qb, kb, vtb,
                                                 nullptr, BB * TT, 3 * CC, CC);
    attn_fwd<<<dim3(TT / 64, BB * HH), 256, 0, stream>>>(qb, kb, vtb, attb);
    gemm_bt<1><<<dim3(64, 8), 256, 0, stream>>>(attb, wprojb, bproj, nullptr,
                                                nullptr, nullptr, out, BB * TT,
                                                CC, CC);
}

// Round 4
// 229.174 us; speedup vs baseline: 2.4871x; 2.4871x over previous
//
#include <hip/hip_runtime.h>
#include <hip/hip_bf16.h>
#include <stdint.h>

// Problem constants
constexpr int BB = 4, TT = 2048, CC = 1024, HH = 16, DD = 64;

typedef __bf16 bf16_t;
typedef bf16_t bf16x8 __attribute__((ext_vector_type(8)));
typedef float f32x4 __attribute__((ext_vector_type(4)));

__device__ __forceinline__ unsigned short f2bf(float f) {
    union { float f; unsigned int u; } v; v.f = f;
    unsigned int u = v.u;
    unsigned int r = u + 0x7fffu + ((u >> 16) & 1u);
    return (unsigned short)(r >> 16);
}

__device__ __forceinline__ f32x4 mfma16(bf16x8 a, bf16x8 b, f32x4 c) {
    return __builtin_amdgcn_mfma_f32_16x16x32_bf16(a, b, c, 0, 0, 0);
}

#define LOAD_LDS16(g, l)                                                      \
    __builtin_amdgcn_global_load_lds(                                         \
        (const __attribute__((address_space(1))) void*)(g),                   \
        (__attribute__((address_space(3))) void*)(l), 16, 0, 0)

// ---------------- f32 -> bf16 convert (n % 4 == 0) ----------------
__global__ __launch_bounds__(256) void cvt_bf16(const float* __restrict__ in,
                                                unsigned short* __restrict__ out,
                                                long n) {
    long i = ((long)blockIdx.x * blockDim.x + threadIdx.x) * 4;
    long stride = (long)gridDim.x * blockDim.x * 4;
    for (; i < n; i += stride) {
        float4 v = *(const float4*)(in + i);
        ushort4 o;
        o.x = f2bf(v.x); o.y = f2bf(v.y); o.z = f2bf(v.z); o.w = f2bf(v.w);
        *(ushort4*)(out + i) = o;
    }
}

// ---------------- GEMM: C[m,n] = sum_k A[m,k]*Bw[n,k] + bias[n] ----------------
template <int MODE>
__global__ __launch_bounds__(256, 2) void gemm_bt(
    const unsigned short* __restrict__ A,    // [M][K] bf16
    const unsigned short* __restrict__ Bw,   // [N][K] bf16
    const float* __restrict__ bias,          // [N]
    unsigned short* __restrict__ qb, unsigned short* __restrict__ kb,
    unsigned short* __restrict__ vtb, float* __restrict__ outf,
    int M, int N, int K) {
    __shared__ unsigned short As[2][128 * 32];
    __shared__ unsigned short Bs[2][128 * 32];
    const int tid = threadIdx.x;
    const int w = tid >> 6, lane = tid & 63;
    const int g = lane >> 4, q16 = lane & 15;
    const int wr = w >> 1, wc = w & 1;
    const int mbase = blockIdx.x * 128;
    const int nbase = blockIdx.y * 128;
    const int srow = lane >> 2;
    const int scol = (lane & 3) * 8;

    f32x4 acc[4][4];
#pragma unroll
    for (int i = 0; i < 4; ++i)
#pragma unroll
        for (int j = 0; j < 4; ++j) acc[i][j] = (f32x4){0.f, 0.f, 0.f, 0.f};

    const int nk = K >> 5;

    auto stage = [&](int buf, int t) {
        const int k0 = t << 5;
#pragma unroll
        for (int ii = 0; ii < 2; ++ii) {
            const int i = w + ii * 4;
            const unsigned short* ga =
                A + (long)(mbase + i * 16 + srow) * K + k0 + scol;
            LOAD_LDS16(ga, &As[buf][i * 512]);
            const unsigned short* gb =
                Bw + (long)(nbase + i * 16 + srow) * K + k0 + scol;
            LOAD_LDS16(gb, &Bs[buf][i * 512]);
        }
    };

    stage(0, 0);
    __syncthreads();
    int cur = 0;
    for (int t = 0; t < nk; ++t) {
        if (t + 1 < nk) stage(cur ^ 1, t + 1);
        bf16x8 af[4], bfr[4];
#pragma unroll
        for (int mi = 0; mi < 4; ++mi)
            af[mi] = *(const bf16x8*)&As[cur][(wr * 64 + mi * 16 + q16) * 32 + 8 * g];
#pragma unroll
        for (int ni = 0; ni < 4; ++ni)
            bfr[ni] = *(const bf16x8*)&Bs[cur][(wc * 64 + ni * 16 + q16) * 32 + 8 * g];
#pragma unroll
        for (int mi = 0; mi < 4; ++mi)
#pragma unroll
            for (int ni = 0; ni < 4; ++ni)
                acc[mi][ni] = mfma16(af[mi], bfr[ni], acc[mi][ni]);
        __syncthreads();
        cur ^= 1;
    }

#pragma unroll
    for (int mi = 0; mi < 4; ++mi) {
#pragma unroll
        for (int ni = 0; ni < 4; ++ni) {
            const int n = nbase + wc * 64 + ni * 16 + q16;
            const float bv = bias[n];
#pragma unroll
            for (int r = 0; r < 4; ++r) {
                const int m = mbase + wr * 64 + mi * 16 + 4 * g + r;
                const float val = acc[mi][ni][r] + bv;
                if (MODE == 0) {
                    const int which = n >> 10, rem = n & 1023;
                    const int h = rem >> 6, d = rem & 63;
                    const int b = m >> 11, t = m & 2047;
                    const long bh = (long)(b * HH + h);
                    if (which == 0)
                        qb[(bh * TT + t) * DD + d] = f2bf(val * 0.125f);
                    else if (which == 1)
                        kb[(bh * TT + t) * DD + d] = f2bf(val);
                    else
                        vtb[(bh * DD + d) * TT + t] = f2bf(val);
                } else {
                    outf[(long)m * N + n] = val;
                }
            }
        }
    }
}

// ---------------- causal flash attention (swapped QK^T + LDS-staged K/V) ----
// grid: flat 2048 blocks, XCD-swizzled so each XCD owns 8 bh (K+V = 4MB = L2).
// Block: 4 waves, QBLK=64 (wave owns 16 q-rows), KVBLK=64.
// K-tile [64][64] and V^T-tile [64][64] staged via global_load_lds (16B),
// double-buffered; XOR-swizzle col16 ^= row&7 applied on the GLOBAL source
// (LDS dest linear, rule #21), reads use slot=(g^(q16&7))<<3 (slot1=slot0^32).
// Softmax: swapped QK^T -> lane owns one q-row; in-register max/sum + 2 shfl.
__global__ __launch_bounds__(256, 3) void attn_fwd(
    const unsigned short* __restrict__ qb, const unsigned short* __restrict__ kb,
    const unsigned short* __restrict__ vtb, unsigned short* __restrict__ attb) {
    __shared__ __align__(16) unsigned short Ks[2][64 * 64];
    __shared__ __align__(16) unsigned short Vs[2][64 * 64];
    __shared__ __align__(16) unsigned short plds[4][16 * 72];
    const int tid = threadIdx.x;
    const int w = tid >> 6, lane = tid & 63;
    const int g = lane >> 4, q16 = lane & 15;
    const int bid = blockIdx.x;
    const int swz = (bid & 7) * 256 + (bid >> 3);   // 2048 % 8 == 0: bijective
    const int bx = swz & 31, bh = swz >> 5;
    const int b = bh >> 4, h = bh & 15;
    const int qbase = bx * 64 + w * 16;

    const unsigned short* Q = qb + (long)bh * TT * DD;
    const unsigned short* Kp = kb + (long)bh * TT * DD;
    const unsigned short* Vt = vtb + (long)bh * DD * TT;

    // staging: thread t covers row srow=(t>>3)&31 (+32 for 2nd instr),
    // 16B slot (t&7), source-swizzled by row&7.
    const int srow = tid >> 3;                       // 0..31
    const int ssl = ((tid & 7) ^ (srow & 7)) * 8;    // swizzled col (shorts)
    unsigned short* kdst0 = &Ks[0][0] + w * 512;     // wave-uniform dests
    unsigned short* vdst0 = &Vs[0][0] + w * 512;

    auto stageKV = [&](int buf, int kt) {
        const long kb0 = (long)kt * 64;
        const unsigned short* gk = Kp + (kb0 + srow) * DD + ssl;
        const unsigned short* gv = Vt + (long)srow * TT + kb0 + ssl;
        unsigned short* kd = kdst0 + buf * 4096;
        unsigned short* vd = vdst0 + buf * 4096;
        LOAD_LDS16(gk, kd);
        LOAD_LDS16(gk + 32l * DD, kd + 2048);
        LOAD_LDS16(gv, vd);
        LOAD_LDS16(gv + 32l * TT, vd + 2048);
    };

    // Q as B-fragment: lane loads Q row (qbase+q16), k-slice 8g (+32)
    bf16x8 aq0 = *(const bf16x8*)&Q[(qbase + q16) * DD + 8 * g];
    bf16x8 aq1 = *(const bf16x8*)&Q[(qbase + q16) * DD + 32 + 8 * g];

    f32x4 acc[4];
#pragma unroll
    for (int i = 0; i < 4; ++i) acc[i] = (f32x4){0.f, 0.f, 0.f, 0.f};
    float mrow = -1e30f, lrow = 0.f;

    const int slot0 = (g ^ (q16 & 7)) << 3;  // swizzled 16B slot (shorts)
    const int nkt = bx + 1;
    stageKV(0, 0);
    __syncthreads();
    int cur = 0;
    for (int kt = 0; kt < nkt; ++kt) {
        if (kt + 1 < nkt) stageKV(cur ^ 1, kt + 1);
        const int kbase = kt * 64;
        f32x4 p[4];
#pragma unroll
        for (int s = 0; s < 4; ++s) p[s] = (f32x4){0.f, 0.f, 0.f, 0.f};
#pragma unroll
        for (int s = 0; s < 4; ++s) {
            const int kr = (16 * s + q16) * 64;
            bf16x8 bk0 = *(const bf16x8*)&Ks[cur][kr + slot0];
            bf16x8 bk1 = *(const bf16x8*)&Ks[cur][kr + (slot0 ^ 32)];
            p[s] = mfma16(bk0, aq0, p[s]);
            p[s] = mfma16(bk1, aq1, p[s]);
        }
        const int q = qbase + q16;
        if (kt == nkt - 1) {  // only the last tile can contain k > q
#pragma unroll
            for (int s = 0; s < 4; ++s)
#pragma unroll
                for (int r = 0; r < 4; ++r)
                    if (kbase + 16 * s + 4 * g + r > q) p[s][r] = -1e30f;
        }
        // row max: in-register + xor over lanes sharing q16
        float t = fmaxf(fmaxf(p[0][0], p[0][1]), fmaxf(p[0][2], p[0][3]));
#pragma unroll
        for (int s = 1; s < 4; ++s)
            t = fmaxf(t, fmaxf(fmaxf(p[s][0], p[s][1]), fmaxf(p[s][2], p[s][3])));
        t = fmaxf(t, __shfl_xor(t, 16));
        t = fmaxf(t, __shfl_xor(t, 32));
        const float nm = fmaxf(mrow, t);
        const float fs = __expf(mrow - nm);
        mrow = nm;
        float ssum = 0.f;
#pragma unroll
        for (int s = 0; s < 4; ++s)
#pragma unroll
            for (int r = 0; r < 4; ++r) {
                p[s][r] = __expf(p[s][r] - nm);
                ssum += p[s][r];
            }
        ssum += __shfl_xor(ssum, 16);
        ssum += __shfl_xor(ssum, 32);
        lrow = lrow * fs + ssum;
        // broadcast fs into acc layout (q = qbase + 4g + r)
        float fr[4];
#pragma unroll
        for (int r = 0; r < 4; ++r) fr[r] = __shfl(fs, 4 * g + r);
#pragma unroll
        for (int ni = 0; ni < 4; ++ni)
#pragma unroll
            for (int r = 0; r < 4; ++r) acc[ni][r] *= fr[r];
        // P -> LDS: lane holds P[q=q16][k=16s+4g+r]; packed 8B writes
#pragma unroll
        for (int s = 0; s < 4; ++s) {
            ushort4 pk;
            pk.x = f2bf(p[s][0]); pk.y = f2bf(p[s][1]);
            pk.z = f2bf(p[s][2]); pk.w = f2bf(p[s][3]);
            *(ushort4*)&plds[w][q16 * 72 + 16 * s + 4 * g] = pk;
        }
        bf16x8 pa0 = *(const bf16x8*)&plds[w][q16 * 72 + 8 * g];
        bf16x8 pa1 = *(const bf16x8*)&plds[w][q16 * 72 + 32 + 8 * g];
        // PV: A = P[q][k], B = V^T rows (d) from LDS (same swizzle as K)
#pragma unroll
        for (int ni = 0; ni < 4; ++ni) {
            const int vr = (ni * 16 + q16) * 64;
            bf16x8 bv0 = *(const bf16x8*)&Vs[cur][vr + slot0];
            bf16x8 bv1 = *(const bf16x8*)&Vs[cur][vr + (slot0 ^ 32)];
            acc[ni] = mfma16(pa0, bv0, acc[ni]);
            acc[ni] = mfma16(pa1, bv1, acc[ni]);
        }
        __syncthreads();
        cur ^= 1;
    }
    // broadcast lrow into acc layout, write out
    float inv[4];
#pragma unroll
    for (int r = 0; r < 4; ++r) inv[r] = 1.0f / __shfl(lrow, 4 * g + r);
#pragma unroll
    for (int ni = 0; ni < 4; ++ni)
#pragma unroll
        for (int r = 0; r < 4; ++r) {
            const int q = qbase + 4 * g + r;
            const int d = ni * 16 + q16;
            attb[(((long)b * TT + q) * HH + h) * DD + d] =
                f2bf(acc[ni][r] * inv[r]);
        }
}

extern "C" void kernel_launch(void* const* d_in, const int* in_sizes, int n_in,
                              void* d_out, int out_size, void* d_ws, size_t ws_size,
                              hipStream_t stream) {
    const float* x = (const float*)d_in[0];
    const float* Wqkv = (const float*)d_in[1];
    const float* bqkv = (const float*)d_in[2];
    const float* Wproj = (const float*)d_in[3];
    const float* bproj = (const float*)d_in[4];
    float* out = (float*)d_out;

    char* ws = (char*)d_ws;
    unsigned short* xb = (unsigned short*)(ws);                  // 16 MB (reused as attb)
    unsigned short* wqkvb = (unsigned short*)(ws + (16l << 20)); // 6 MB
    unsigned short* wprojb = (unsigned short*)(ws + (22l << 20));// 2 MB
    unsigned short* qb = (unsigned short*)(ws + (24l << 20));    // 16 MB
    unsigned short* kb = (unsigned short*)(ws + (40l << 20));    // 16 MB
    unsigned short* vtb = (unsigned short*)(ws + (56l << 20));   // 16 MB
    unsigned short* attb = xb;  // x dead after QKV GEMM; reuse

    cvt_bf16<<<2048, 256, 0, stream>>>(x, xb, (long)BB * TT * CC);
    cvt_bf16<<<2048, 256, 0, stream>>>(Wqkv, wqkvb, (long)3 * CC * CC);
    cvt_bf16<<<1024, 256, 0, stream>>>(Wproj, wprojb, (long)CC * CC);

    gemm_bt<0><<<dim3(64, 24), 256, 0, stream>>>(xb, wqkvb, bqkv, qb, kb, vtb,
                                                 nullptr, BB * TT, 3 * CC, CC);
    attn_fwd<<<2048, 256, 0, stream>>>(qb, kb, vtb, attb);
    gemm_bt<1><<<dim3(64, 8), 256, 0, stream>>>(attb, wprojb, bproj, nullptr,
                                                nullptr, nullptr, out, BB * TT,
                                                CC, CC);
}

// Round 5
// 218.866 us; speedup vs baseline: 2.6042x; 1.0471x over previous
//
#include <hip/hip_runtime.h>
#include <hip/hip_bf16.h>
#include <stdint.h>

// Problem constants
constexpr int BB = 4, TT = 2048, CC = 1024, HH = 16, DD = 64;

typedef __bf16 bf16_t;
typedef bf16_t bf16x8 __attribute__((ext_vector_type(8)));
typedef float f32x4 __attribute__((ext_vector_type(4)));

// Native cast: compiler emits v_cvt_pk_bf16_f32 for adjacent pairs (RNE).
__device__ __forceinline__ unsigned short f2bf(float f) {
    union { __bf16 h; unsigned short u; } v;
    v.h = (__bf16)f;
    return v.u;
}

__device__ __forceinline__ f32x4 mfma16(bf16x8 a, bf16x8 b, f32x4 c) {
    return __builtin_amdgcn_mfma_f32_16x16x32_bf16(a, b, c, 0, 0, 0);
}

#define LOAD_LDS16(g, l)                                                      \
    __builtin_amdgcn_global_load_lds(                                         \
        (const __attribute__((address_space(1))) void*)(g),                   \
        (__attribute__((address_space(3))) void*)(l), 16, 0, 0)

// ---------------- f32 -> bf16 convert (n % 4 == 0) ----------------
__global__ __launch_bounds__(256) void cvt_bf16(const float* __restrict__ in,
                                                unsigned short* __restrict__ out,
                                                long n) {
    long i = ((long)blockIdx.x * blockDim.x + threadIdx.x) * 4;
    long stride = (long)gridDim.x * blockDim.x * 4;
    for (; i < n; i += stride) {
        float4 v = *(const float4*)(in + i);
        ushort4 o;
        o.x = f2bf(v.x); o.y = f2bf(v.y); o.z = f2bf(v.z); o.w = f2bf(v.w);
        *(ushort4*)(out + i) = o;
    }
}

// ---------------- GEMM: C[m,n] = sum_k A[m,k]*Bw[n,k] + bias[n] ----------------
template <int MODE>
__global__ __launch_bounds__(256, 2) void gemm_bt(
    const unsigned short* __restrict__ A,    // [M][K] bf16
    const unsigned short* __restrict__ Bw,   // [N][K] bf16
    const float* __restrict__ bias,          // [N]
    unsigned short* __restrict__ qb, unsigned short* __restrict__ kb,
    unsigned short* __restrict__ vtb, float* __restrict__ outf,
    int M, int N, int K) {
    __shared__ unsigned short As[2][128 * 32];
    __shared__ unsigned short Bs[2][128 * 32];
    const int tid = threadIdx.x;
    const int w = tid >> 6, lane = tid & 63;
    const int g = lane >> 4, q16 = lane & 15;
    const int wr = w >> 1, wc = w & 1;
    const int mbase = blockIdx.x * 128;
    const int nbase = blockIdx.y * 128;
    const int srow = lane >> 2;
    const int scol = (lane & 3) * 8;

    f32x4 acc[4][4];
#pragma unroll
    for (int i = 0; i < 4; ++i)
#pragma unroll
        for (int j = 0; j < 4; ++j) acc[i][j] = (f32x4){0.f, 0.f, 0.f, 0.f};

    const int nk = K >> 5;

    auto stage = [&](int buf, int t) {
        const int k0 = t << 5;
#pragma unroll
        for (int ii = 0; ii < 2; ++ii) {
            const int i = w + ii * 4;
            const unsigned short* ga =
                A + (long)(mbase + i * 16 + srow) * K + k0 + scol;
            LOAD_LDS16(ga, &As[buf][i * 512]);
            const unsigned short* gb =
                Bw + (long)(nbase + i * 16 + srow) * K + k0 + scol;
            LOAD_LDS16(gb, &Bs[buf][i * 512]);
        }
    };

    stage(0, 0);
    __syncthreads();
    int cur = 0;
    for (int t = 0; t < nk; ++t) {
        if (t + 1 < nk) stage(cur ^ 1, t + 1);
        bf16x8 af[4], bfr[4];
#pragma unroll
        for (int mi = 0; mi < 4; ++mi)
            af[mi] = *(const bf16x8*)&As[cur][(wr * 64 + mi * 16 + q16) * 32 + 8 * g];
#pragma unroll
        for (int ni = 0; ni < 4; ++ni)
            bfr[ni] = *(const bf16x8*)&Bs[cur][(wc * 64 + ni * 16 + q16) * 32 + 8 * g];
#pragma unroll
        for (int mi = 0; mi < 4; ++mi)
#pragma unroll
            for (int ni = 0; ni < 4; ++ni)
                acc[mi][ni] = mfma16(af[mi], bfr[ni], acc[mi][ni]);
        __syncthreads();
        cur ^= 1;
    }

#pragma unroll
    for (int mi = 0; mi < 4; ++mi) {
#pragma unroll
        for (int ni = 0; ni < 4; ++ni) {
            const int n = nbase + wc * 64 + ni * 16 + q16;
            const float bv = bias[n];
#pragma unroll
            for (int r = 0; r < 4; ++r) {
                const int m = mbase + wr * 64 + mi * 16 + 4 * g + r;
                const float val = acc[mi][ni][r] + bv;
                if (MODE == 0) {
                    const int which = n >> 10, rem = n & 1023;
                    const int h = rem >> 6, d = rem & 63;
                    const int b = m >> 11, t = m & 2047;
                    const long bh = (long)(b * HH + h);
                    if (which == 0)
                        qb[(bh * TT + t) * DD + d] = f2bf(val * 0.125f);
                    else if (which == 1)
                        kb[(bh * TT + t) * DD + d] = f2bf(val);
                    else
                        vtb[(bh * DD + d) * TT + t] = f2bf(val);
                } else {
                    outf[(long)m * N + n] = val;
                }
            }
        }
    }
}

// ---------------- causal flash attention (swapped QK^T + LDS-staged K/V) ----
// grid: flat 2048 blocks, XCD-swizzled so each XCD owns 8 bh (K+V = 4MB = L2).
// Block: 4 waves, QBLK=64 (wave owns 16 q-rows), KVBLK=64.
// K/V^T tiles staged via global_load_lds (16B), double-buffered, XOR-swizzled
// on the GLOBAL source (rule #21). plds: stride-64 XOR-swizzled (8B-group
// G' = G ^ (q16&7)) -> floor-optimal banks; LDS = 40960 B = 4 blocks/CU.
// Softmax: swapped QK^T, lane owns one q-row; defer-max (T13, THR=8).
__global__ __launch_bounds__(256, 4) void attn_fwd(
    const unsigned short* __restrict__ qb, const unsigned short* __restrict__ kb,
    const unsigned short* __restrict__ vtb, unsigned short* __restrict__ attb) {
    __shared__ __align__(16) unsigned short Ks[2][64 * 64];
    __shared__ __align__(16) unsigned short Vs[2][64 * 64];
    __shared__ __align__(16) unsigned short plds[4][16 * 64];
    const int tid = threadIdx.x;
    const int w = tid >> 6, lane = tid & 63;
    const int g = lane >> 4, q16 = lane & 15;
    const int bid = blockIdx.x;
    const int swz = (bid & 7) * 256 + (bid >> 3);   // 2048 % 8 == 0: bijective
    const int bx = swz & 31, bh = swz >> 5;
    const int b = bh >> 4, h = bh & 15;
    const int qbase = bx * 64 + w * 16;

    const unsigned short* Q = qb + (long)bh * TT * DD;
    const unsigned short* Kp = kb + (long)bh * TT * DD;
    const unsigned short* Vt = vtb + (long)bh * DD * TT;

    // staging: thread t covers row srow=(t>>3) (+32 for 2nd instr),
    // 16B slot (t&7), source-swizzled by row&7.
    const int srow = tid >> 3;                       // 0..31
    const int ssl = ((tid & 7) ^ (srow & 7)) * 8;    // swizzled col (shorts)
    unsigned short* kdst0 = &Ks[0][0] + w * 512;     // wave-uniform dests
    unsigned short* vdst0 = &Vs[0][0] + w * 512;

    auto stageKV = [&](int buf, int kt) {
        const long kb0 = (long)kt * 64;
        const unsigned short* gk = Kp + (kb0 + srow) * DD + ssl;
        const unsigned short* gv = Vt + (long)srow * TT + kb0 + ssl;
        unsigned short* kd = kdst0 + buf * 4096;
        unsigned short* vd = vdst0 + buf * 4096;
        LOAD_LDS16(gk, kd);
        LOAD_LDS16(gk + 32l * DD, kd + 2048);
        LOAD_LDS16(gv, vd);
        LOAD_LDS16(gv + 32l * TT, vd + 2048);
    };

    // Q as B-fragment: lane loads Q row (qbase+q16), k-slice 8g (+32)
    bf16x8 aq0 = *(const bf16x8*)&Q[(qbase + q16) * DD + 8 * g];
    bf16x8 aq1 = *(const bf16x8*)&Q[(qbase + q16) * DD + 32 + 8 * g];

    f32x4 acc[4];
#pragma unroll
    for (int i = 0; i < 4; ++i) acc[i] = (f32x4){0.f, 0.f, 0.f, 0.f};
    float mrow = -1e30f, lrow = 0.f;

    const int slot0 = (g ^ (q16 & 7)) << 3;  // swizzled 16B slot (shorts)
    const int nkt = bx + 1;
    stageKV(0, 0);
    __syncthreads();
    int cur = 0;
    for (int kt = 0; kt < nkt; ++kt) {
        if (kt + 1 < nkt) stageKV(cur ^ 1, kt + 1);
        const int kbase = kt * 64;
        f32x4 p[4];
#pragma unroll
        for (int s = 0; s < 4; ++s) p[s] = (f32x4){0.f, 0.f, 0.f, 0.f};
#pragma unroll
        for (int s = 0; s < 4; ++s) {
            const int kr = (16 * s + q16) * 64;
            bf16x8 bk0 = *(const bf16x8*)&Ks[cur][kr + slot0];
            bf16x8 bk1 = *(const bf16x8*)&Ks[cur][kr + (slot0 ^ 32)];
            p[s] = mfma16(bk0, aq0, p[s]);
            p[s] = mfma16(bk1, aq1, p[s]);
        }
        const int q = qbase + q16;
        if (kt == nkt - 1) {  // only the last tile can contain k > q
#pragma unroll
            for (int s = 0; s < 4; ++s)
#pragma unroll
                for (int r = 0; r < 4; ++r)
                    if (kbase + 16 * s + 4 * g + r > q) p[s][r] = -1e30f;
        }
        // row max: in-register + xor over lanes sharing q16
        float t = fmaxf(fmaxf(p[0][0], p[0][1]), fmaxf(p[0][2], p[0][3]));
#pragma unroll
        for (int s = 1; s < 4; ++s)
            t = fmaxf(t, fmaxf(fmaxf(p[s][0], p[s][1]), fmaxf(p[s][2], p[s][3])));
        t = fmaxf(t, __shfl_xor(t, 16));
        t = fmaxf(t, __shfl_xor(t, 32));
        // defer-max (T13): skip rescale while tile max stays within THR=8
        if (__all(t - mrow <= 8.0f)) {
            float ssum = 0.f;
#pragma unroll
            for (int s = 0; s < 4; ++s)
#pragma unroll
                for (int r = 0; r < 4; ++r) {
                    p[s][r] = __expf(p[s][r] - mrow);
                    ssum += p[s][r];
                }
            ssum += __shfl_xor(ssum, 16);
            ssum += __shfl_xor(ssum, 32);
            lrow += ssum;
        } else {
            const float nm = fmaxf(mrow, t);
            const float fs = __expf(mrow - nm);
            mrow = nm;
            float ssum = 0.f;
#pragma unroll
            for (int s = 0; s < 4; ++s)
#pragma unroll
                for (int r = 0; r < 4; ++r) {
                    p[s][r] = __expf(p[s][r] - nm);
                    ssum += p[s][r];
                }
            ssum += __shfl_xor(ssum, 16);
            ssum += __shfl_xor(ssum, 32);
            lrow = lrow * fs + ssum;
            // broadcast fs into acc layout (q = qbase + 4g + r)
            float fr[4];
#pragma unroll
            for (int r = 0; r < 4; ++r) fr[r] = __shfl(fs, 4 * g + r);
#pragma unroll
            for (int ni = 0; ni < 4; ++ni)
#pragma unroll
                for (int r = 0; r < 4; ++r) acc[ni][r] *= fr[r];
        }
        // P -> LDS: lane holds P[q=q16][k=16s+4g+r]; 8B writes, G-swizzled
#pragma unroll
        for (int s = 0; s < 4; ++s) {
            ushort4 pk;
            pk.x = f2bf(p[s][0]); pk.y = f2bf(p[s][1]);
            pk.z = f2bf(p[s][2]); pk.w = f2bf(p[s][3]);
            const int Gp = ((2 * s + (g >> 1)) ^ (q16 & 7)) * 8 + (g & 1) * 4;
            *(ushort4*)&plds[w][q16 * 64 + Gp] = pk;
        }
        bf16x8 pa0 = *(const bf16x8*)&plds[w][q16 * 64 + slot0];
        bf16x8 pa1 = *(const bf16x8*)&plds[w][q16 * 64 + (slot0 ^ 32)];
        // PV: A = P[q][k], B = V^T rows (d) from LDS (same swizzle as K)
#pragma unroll
        for (int ni = 0; ni < 4; ++ni) {
            const int vr = (ni * 16 + q16) * 64;
            bf16x8 bv0 = *(const bf16x8*)&Vs[cur][vr + slot0];
            bf16x8 bv1 = *(const bf16x8*)&Vs[cur][vr + (slot0 ^ 32)];
            acc[ni] = mfma16(pa0, bv0, acc[ni]);
            acc[ni] = mfma16(pa1, bv1, acc[ni]);
        }
        __syncthreads();
        cur ^= 1;
    }
    // broadcast lrow into acc layout, write out
    float inv[4];
#pragma unroll
    for (int r = 0; r < 4; ++r) inv[r] = 1.0f / __shfl(lrow, 4 * g + r);
#pragma unroll
    for (int ni = 0; ni < 4; ++ni)
#pragma unroll
        for (int r = 0; r < 4; ++r) {
            const int q = qbase + 4 * g + r;
            const int d = ni * 16 + q16;
            attb[(((long)b * TT + q) * HH + h) * DD + d] =
                f2bf(acc[ni][r] * inv[r]);
        }
}

extern "C" void kernel_launch(void* const* d_in, const int* in_sizes, int n_in,
                              void* d_out, int out_size, void* d_ws, size_t ws_size,
                              hipStream_t stream) {
    const float* x = (const float*)d_in[0];
    const float* Wqkv = (const float*)d_in[1];
    const float* bqkv = (const float*)d_in[2];
    const float* Wproj = (const float*)d_in[3];
    const float* bproj = (const float*)d_in[4];
    float* out = (float*)d_out;

    char* ws = (char*)d_ws;
    unsigned short* xb = (unsigned short*)(ws);                  // 16 MB (reused as attb)
    unsigned short* wqkvb = (unsigned short*)(ws + (16l << 20)); // 6 MB
    unsigned short* wprojb = (unsigned short*)(ws + (22l << 20));// 2 MB
    unsigned short* qb = (unsigned short*)(ws + (24l << 20));    // 16 MB
    unsigned short* kb = (unsigned short*)(ws + (40l << 20));    // 16 MB
    unsigned short* vtb = (unsigned short*)(ws + (56l << 20));   // 16 MB
    unsigned short* attb = xb;  // x dead after QKV GEMM; reuse

    cvt_bf16<<<2048, 256, 0, stream>>>(x, xb, (long)BB * TT * CC);
    cvt_bf16<<<2048, 256, 0, stream>>>(Wqkv, wqkvb, (long)3 * CC * CC);
    cvt_bf16<<<1024, 256, 0, stream>>>(Wproj, wprojb, (long)CC * CC);

    gemm_bt<0><<<dim3(64, 24), 256, 0, stream>>>(xb, wqkvb, bqkv, qb, kb, vtb,
                                                 nullptr, BB * TT, 3 * CC, CC);
    attn_fwd<<<2048, 256, 0, stream>>>(qb, kb, vtb, attb);
    gemm_bt<1><<<dim3(64, 8), 256, 0, stream>>>(attb, wprojb, bproj, nullptr,
                                                nullptr, nullptr, out, BB * TT,
                                                CC, CC);
}